// Round 3
// baseline (1345.583 us; speedup 1.0000x reference)
//
#include <hip/hip_runtime.h>

typedef __bf16 bf16_t;
typedef bf16_t bf16x8 __attribute__((ext_vector_type(8)));
typedef bf16_t bf16x4 __attribute__((ext_vector_type(4)));
typedef float f32x4 __attribute__((ext_vector_type(4)));

#define DEVI static __device__ __forceinline__
#define MFMA16(a, b, c) __builtin_amdgcn_mfma_f32_16x16x32_bf16((a), (b), (c), 0, 0, 0)

constexpr int BB = 64;
constexpr int NN = 4096;
constexpr int DD = 256;
constexpr int KS = 11;     // real slots
constexpr int KP = 16;     // padded slots (MFMA tile)
constexpr float EPS_A = 1e-8f;
constexpr float LNEPS = 1e-5f;
constexpr float SCALE = 0.0625f;   // 256^-0.5
constexpr int MR = BB * KP;        // 1024 padded slot rows
constexpr int NSPLIT = 8;          // blocks per batch in fused attention
constexpr int ASTR = 40;           // attn LDS row stride

DEVI float wredf(float v) {
#pragma unroll
  for (int o = 32; o > 0; o >>= 1) v += __shfl_xor(v, o, 64);
  return v;
}

DEVI float sigm(float x) { return 1.f / (1.f + __expf(-x)); }

// ---------------- prep: fp32 -> bf16 weights ----------------
__global__ void prep_weights_k(
    const float* __restrict__ s0, const float* __restrict__ s1, const float* __restrict__ s2,
    const float* __restrict__ s3, const float* __restrict__ s4, const float* __restrict__ s5,
    const float* __restrict__ s6,
    bf16_t* d0, bf16_t* d1, bf16_t* d2, bf16_t* d3, bf16_t* d4, bf16_t* d5, bf16_t* d6) {
  int i = blockIdx.x * 256 + threadIdx.x;
  const float* s; bf16_t* d; int o;
  if      (i < 65536)  { s = s0; d = d0; o = i; }
  else if (i < 131072) { s = s1; d = d1; o = i - 65536; }
  else if (i < 196608) { s = s2; d = d2; o = i - 131072; }
  else if (i < 393216) { s = s3; d = d3; o = i - 196608; }
  else if (i < 589824) { s = s4; d = d4; o = i - 393216; }
  else if (i < 720896) { s = s5; d = d5; o = i - 589824; }
  else                 { s = s6; d = d6; o = i - 720896; }
  d[o] = (bf16_t)s[o];
}

// ---------------- LN(inputs) -> x_bf (one wave per row) ----------------
__global__ void ln_inputs_k(const float* __restrict__ x, const float* __restrict__ w,
                            const float* __restrict__ bsk, bf16_t* __restrict__ o) {
  const int wvi = threadIdx.x >> 6, lane = threadIdx.x & 63;
  const long row = (long)blockIdx.x * 4 + wvi;
  const float4 v = ((const float4*)(x + row * DD))[lane];
  float s = v.x + v.y + v.z + v.w;
  float s2 = v.x * v.x + v.y * v.y + v.z * v.z + v.w * v.w;
  s = wredf(s); s2 = wredf(s2);
  const float mean = s * (1.f / DD);
  const float var = s2 * (1.f / DD) - mean * mean;
  const float rstd = rsqrtf(var + LNEPS);
  const float4 w4 = ((const float4*)w)[lane];
  const float4 b4 = ((const float4*)bsk)[lane];
  bf16x4 ov;
  ov[0] = (bf16_t)((v.x - mean) * rstd * w4.x + b4.x);
  ov[1] = (bf16_t)((v.y - mean) * rstd * w4.y + b4.y);
  ov[2] = (bf16_t)((v.z - mean) * rstd * w4.z + b4.z);
  ov[3] = (bf16_t)((v.w - mean) * rstd * w4.w + b4.w);
  ((bf16x4*)(o + row * DD))[lane] = ov;
}

// ---------------- big GEMMs merged: k = x@Wk^T (mode0) and vT = (x@Wv^T)^T (mode1) ----
__global__ __launch_bounds__(256) void gemm_kv_k(const bf16_t* __restrict__ X,
                                                 const bf16_t* __restrict__ Wk,
                                                 const bf16_t* __restrict__ Wv,
                                                 bf16_t* __restrict__ kout,
                                                 bf16_t* __restrict__ vout) {
  __shared__ bf16_t As[128 * 72];
  __shared__ bf16_t Bs[256 * 72];
  const int bid = blockIdx.x;
  int mode, bx, by;
  if (bid < 2048) { mode = 0; bx = bid & 1023; by = bid >> 10; }
  else            { mode = 1; bx = bid - 2048; by = 0; }
  const bf16_t* Ap; const bf16_t* Bp;
  if (mode == 0) { Ap = Wk + (long)by * 128 * DD; Bp = X + (long)bx * 256 * DD; }
  else           { Ap = X + (long)bx * 128 * DD; Bp = Wv; }
  const int tid = threadIdx.x;
  const int wvi = tid >> 6, lane = tid & 63;
  const int c = lane & 15, q = lane >> 4;
  const int mh = wvi >> 1, nh = wvi & 1;   // wave tile: 64 m x 128 n
  f32x4 acc[4][8];
#pragma unroll
  for (int a = 0; a < 4; a++)
#pragma unroll
    for (int b = 0; b < 8; b++) acc[a][b] = (f32x4){0.f, 0.f, 0.f, 0.f};
  for (int kb = 0; kb < DD; kb += 64) {
#pragma unroll
    for (int it = 0; it < 4; ++it) {
      int id = it * 256 + tid, r = id >> 3, ch = id & 7;
      *(bf16x8*)(As + r * 72 + ch * 8) = *(const bf16x8*)(Ap + (long)r * DD + kb + ch * 8);
    }
#pragma unroll
    for (int it = 0; it < 8; ++it) {
      int id = it * 256 + tid, r = id >> 3, ch = id & 7;
      *(bf16x8*)(Bs + r * 72 + ch * 8) = *(const bf16x8*)(Bp + (long)r * DD + kb + ch * 8);
    }
    __syncthreads();
#pragma unroll
    for (int ks = 0; ks < 2; ++ks) {
      bf16x8 af[4], bfr[8];
#pragma unroll
      for (int mt = 0; mt < 4; mt++)
        af[mt] = *(const bf16x8*)(As + (mh * 64 + mt * 16 + c) * 72 + ks * 32 + q * 8);
#pragma unroll
      for (int nt = 0; nt < 8; nt++)
        bfr[nt] = *(const bf16x8*)(Bs + (nh * 128 + nt * 16 + c) * 72 + ks * 32 + q * 8);
#pragma unroll
      for (int mt = 0; mt < 4; mt++)
#pragma unroll
        for (int nt = 0; nt < 8; nt++)
          acc[mt][nt] = MFMA16(af[mt], bfr[nt], acc[mt][nt]);
    }
    __syncthreads();
  }
#pragma unroll
  for (int mt = 0; mt < 4; mt++) {
#pragma unroll
    for (int nt = 0; nt < 8; nt++) {
      bf16x4 o;
#pragma unroll
      for (int r = 0; r < 4; r++) o[r] = (bf16_t)acc[mt][nt][r];
      if (mode == 0) {
        int dg = by * 128 + mh * 64 + mt * 16 + q * 4;
        long ng = (long)bx * 256 + nh * 128 + nt * 16 + c;
        *(bf16x4*)(kout + ng * DD + dg) = o;                   // k[row][d]
      } else {
        long ng = (long)bx * 128 + mh * 64 + mt * 16 + q * 4;
        int d = nh * 128 + nt * 16 + c;
        long b = ng >> 12; int nin = (int)(ng & 4095);
        *(bf16x4*)(vout + (b * DD + d) * NN + nin) = o;        // vT[b][d][n]
      }
    }
  }
}

// ---------------- FUSED attention: dots -> softmax(K axis) -> PV, block-reduced ----
// grid: B*NSPLIT blocks, 256 thr. Output: per-block fp32 partial upd_part[bid][16][256].
__global__ __launch_bounds__(256) void fused_attn_k(const bf16_t* __restrict__ q_bf,
                                                    const bf16_t* __restrict__ k_bf,
                                                    const bf16_t* __restrict__ vT_bf,
                                                    float* __restrict__ upd_part,
                                                    float* __restrict__ rowsum) {
  const int b = blockIdx.x >> 3, sp = blockIdx.x & 7;
  const int wvi = threadIdx.x >> 6, lane = threadIdx.x & 63;
  const int c = lane & 15, q = lane >> 4;

  __shared__ bf16_t att_s[4][16 * ASTR];
  __shared__ float sP[4][KP * DD];
  bf16_t* as = att_s[wvi];

  const bf16_t* qp = q_bf + (long)b * KP * DD;
  bf16x8 af[8];
#pragma unroll
  for (int kc = 0; kc < 8; kc++) af[kc] = *(const bf16x8*)(qp + c * DD + kc * 32 + q * 8);

  f32x4 pacc[16];
#pragma unroll
  for (int dt = 0; dt < 16; dt++) pacc[dt] = (f32x4){0.f, 0.f, 0.f, 0.f};
  float rs[4] = {0.f, 0.f, 0.f, 0.f};

  const int n_base = sp * (NN / NSPLIT) + wvi * 128;
  const bf16_t* kp = k_bf + (long)b * NN * DD;
  const bf16_t* vp = vT_bf + (long)b * DD * NN;

  for (int ch = 0; ch < 4; ++ch) {
    const int n0 = n_base + ch * 32;
    float v[2][4];
#pragma unroll
    for (int t = 0; t < 2; t++) {
      f32x4 dacc = (f32x4){0.f, 0.f, 0.f, 0.f};
      const bf16_t* bp = kp + (long)(n0 + t * 16 + c) * DD + q * 8;
#pragma unroll
      for (int kc = 0; kc < 8; kc++)
        dacc = MFMA16(af[kc], *(const bf16x8*)(bp + kc * 32), dacc);
#pragma unroll
      for (int r = 0; r < 4; r++) {
        float dv = dacc[r] * SCALE;
        if (q * 4 + r >= KS) dv = -1e30f;   // mask pad slots
        v[t][r] = dv;
      }
      float m4 = fmaxf(fmaxf(v[t][0], v[t][1]), fmaxf(v[t][2], v[t][3]));
      m4 = fmaxf(m4, __shfl_xor(m4, 16, 64));
      m4 = fmaxf(m4, __shfl_xor(m4, 32, 64));
      float s4 = 0.f;
#pragma unroll
      for (int r = 0; r < 4; r++) { v[t][r] = __expf(v[t][r] - m4); s4 += v[t][r]; }
      s4 += __shfl_xor(s4, 16, 64);
      s4 += __shfl_xor(s4, 32, 64);
      const float inv = 1.f / s4;
#pragma unroll
      for (int r = 0; r < 4; r++) {
        float a = v[t][r] * inv + EPS_A;
        rs[r] += a;
        as[(q * 4 + r) * ASTR + t * 16 + c] = (bf16_t)a;
      }
    }
    bf16x8 pa = *(const bf16x8*)(as + c * ASTR + q * 8);
#pragma unroll
    for (int dt = 0; dt < 16; dt++) {
      const bf16_t* bp2 = vp + (long)(dt * 16 + c) * NN + n0 + q * 8;
      pacc[dt] = MFMA16(pa, *(const bf16x8*)(bp2), pacc[dt]);
    }
  }

#pragma unroll
  for (int off = 1; off < 16; off <<= 1)
#pragma unroll
    for (int r = 0; r < 4; r++) rs[r] += __shfl_xor(rs[r], off, 64);
  if (c == 0) {
#pragma unroll
    for (int r = 0; r < 4; r++) atomicAdd(&rowsum[b * KP + q * 4 + r], rs[r]);
  }

  // block-level reduction of the 4 per-wave partials
#pragma unroll
  for (int dt = 0; dt < 16; dt++)
#pragma unroll
    for (int r = 0; r < 4; r++) sP[wvi][(q * 4 + r) * DD + dt * 16 + c] = pacc[dt][r];
  __syncthreads();
  float* up = upd_part + (long)blockIdx.x * (KP * DD);
  for (int idx = threadIdx.x; idx < KP * DD; idx += 256)
    up[idx] = sP[0][idx] + sP[1][idx] + sP[2][idx] + sP[3][idx];
}

// ---------------- slot update mega-kernel: one block per batch ----------------
// MODE 0: init (slots_init -> slots, LN_s, q-proj)
// MODE 1: finalize attn + GRU + MLP + residual + LN_s + q-proj (mid iterations)
// MODE 2: finalize attn + GRU + MLP + residual -> d_out (last iteration)
template <int MODE>
__global__ __launch_bounds__(256, 1) void slot_update_k(
    const float* __restrict__ slots_init, float* __restrict__ slots_g,
    const float* __restrict__ upd_part, float* __restrict__ rowsum,
    bf16_t* __restrict__ q_bf, float* __restrict__ d_out,
    const bf16_t* __restrict__ Wq, const bf16_t* __restrict__ Wih,
    const bf16_t* __restrict__ Whh, const bf16_t* __restrict__ W1,
    const bf16_t* __restrict__ W2,
    const float* __restrict__ b_ih, const float* __restrict__ b_hh,
    const float* __restrict__ b1, const float* __restrict__ b2,
    const float* __restrict__ ln_s_w, const float* __restrict__ ln_s_b,
    const float* __restrict__ ln_p_w, const float* __restrict__ ln_p_b) {
  const int b = blockIdx.x;
  const int tid = threadIdx.x, w = tid >> 6, lane = tid & 63;
  const int c = lane & 15, q = lane >> 4;

  __shared__ float sS[16][264];      // slots fp32 (current state)
  __shared__ bf16_t sA1[16 * 272];   // A-operand staging, K<=256
  __shared__ bf16_t sA2[16 * 528];   // A-operand staging, K<=512
  __shared__ float sMu[16], sRs[16];

  float* slots_b = slots_g + (long)b * KP * DD;

  auto rowstats = [&]() {  // sS -> sMu/sRs (per-row LN stats over 256 cols)
    __syncthreads();
    int row = w * 4 + q;
    float sm = 0.f, sq2 = 0.f;
#pragma unroll
    for (int i = 0; i < 16; i++) { float v = sS[row][i * 16 + c]; sm += v; sq2 += v * v; }
#pragma unroll
    for (int o = 1; o < 16; o <<= 1) { sm += __shfl_xor(sm, o, 64); sq2 += __shfl_xor(sq2, o, 64); }
    if (c == 0) {
      float mu = sm * (1.f / 256.f);
      float var = sq2 * (1.f / 256.f) - mu * mu;
      sMu[row] = mu; sRs[row] = rsqrtf(var + LNEPS);
    }
    __syncthreads();
  };

  if constexpr (MODE == 0) {
    for (int idx = tid; idx < KP * DD; idx += 256) {
      int row = idx >> 8, d = idx & 255;
      float v = (row < KS) ? slots_init[((long)b * KS + row) * DD + d] : 0.f;
      sS[row][d] = v;
      slots_b[idx] = v;
    }
  } else {
    // ---- Stage A: load slots; updA = (sum of 8 partials)/rowsum -> sA1; splA -> sA2
    for (int idx = tid; idx < KP * DD; idx += 256) {
      int row = idx >> 8, d = idx & 255;
      float sv = slots_b[idx];
      sS[row][d] = sv;
      sA2[row * 272 + d] = (bf16_t)sv;
      float s = 0.f;
      const float* up = upd_part + ((long)b * 8) * (KP * DD) + idx;
#pragma unroll
      for (int p = 0; p < 8; p++) s += up[(long)p * (KP * DD)];
      sA1[row * 272 + d] = (bf16_t)(s / rowsum[b * KP + row]);
    }
    __syncthreads();

    // ---- Stage B: gi = updA@Wih^T, gh = splA@Whh^T (each wave: 4 col-tiles per gate) + GRU
    f32x4 air[4], aiz[4], ain[4], ahr[4], ahz[4], ahn[4];
#pragma unroll
    for (int j = 0; j < 4; j++) {
      air[j] = (f32x4){0.f, 0.f, 0.f, 0.f}; aiz[j] = air[j]; ain[j] = air[j];
      ahr[j] = air[j]; ahz[j] = air[j]; ahn[j] = air[j];
    }
    for (int k0 = 0; k0 < 256; k0 += 32) {
      bf16x8 aU = *(const bf16x8*)(sA1 + c * 272 + k0 + q * 8);
      bf16x8 aS = *(const bf16x8*)(sA2 + c * 272 + k0 + q * 8);
#pragma unroll
      for (int j = 0; j < 4; j++) {
        const long colr = (w * 4 + j) * 16 + c;
        air[j] = MFMA16(aU, *(const bf16x8*)(Wih + colr * 256 + k0 + q * 8), air[j]);
        aiz[j] = MFMA16(aU, *(const bf16x8*)(Wih + (colr + 256) * 256 + k0 + q * 8), aiz[j]);
        ain[j] = MFMA16(aU, *(const bf16x8*)(Wih + (colr + 512) * 256 + k0 + q * 8), ain[j]);
        ahr[j] = MFMA16(aS, *(const bf16x8*)(Whh + colr * 256 + k0 + q * 8), ahr[j]);
        ahz[j] = MFMA16(aS, *(const bf16x8*)(Whh + (colr + 256) * 256 + k0 + q * 8), ahz[j]);
        ahn[j] = MFMA16(aS, *(const bf16x8*)(Whh + (colr + 512) * 256 + k0 + q * 8), ahn[j]);
      }
    }
#pragma unroll
    for (int j = 0; j < 4; j++) {
      const int colr = (w * 4 + j) * 16 + c;
      const float bir = b_ih[colr], biz = b_ih[colr + 256], bin = b_ih[colr + 512];
      const float bhr = b_hh[colr], bhz = b_hh[colr + 256], bhn = b_hh[colr + 512];
#pragma unroll
      for (int r = 0; r < 4; r++) {
        const int row = q * 4 + r;
        float rg = sigm(air[j][r] + bir + ahr[j][r] + bhr);
        float zg = sigm(aiz[j][r] + biz + ahz[j][r] + bhz);
        float ng = tanhf(ain[j][r] + bin + rg * (ahn[j][r] + bhn));
        float sp = sS[row][colr];
        sS[row][colr] = (1.f - zg) * ng + zg * sp;   // each thread owns (row,colr)
      }
    }

    // ---- LN_p stats + pbf -> sA1
    rowstats();
    for (int idx = tid; idx < KP * DD; idx += 256) {
      int row = idx >> 8, d = idx & 255;
      sA1[row * 272 + d] = (bf16_t)((sS[row][d] - sMu[row]) * sRs[row] * ln_p_w[d] + ln_p_b[d]);
    }
    __syncthreads();

    // ---- Stage D: h1 = relu(pbf@W1^T + b1) -> sA2 (16 x 512, stride 528)
    f32x4 h[8];
#pragma unroll
    for (int j = 0; j < 8; j++) h[j] = (f32x4){0.f, 0.f, 0.f, 0.f};
    for (int k0 = 0; k0 < 256; k0 += 32) {
      bf16x8 aP = *(const bf16x8*)(sA1 + c * 272 + k0 + q * 8);
#pragma unroll
      for (int j = 0; j < 8; j++) {
        const long col = (w * 8 + j) * 16 + c;
        h[j] = MFMA16(aP, *(const bf16x8*)(W1 + col * 256 + k0 + q * 8), h[j]);
      }
    }
#pragma unroll
    for (int j = 0; j < 8; j++) {
      const int col = (w * 8 + j) * 16 + c;
      const float bb = b1[col];
#pragma unroll
      for (int r = 0; r < 4; r++)
        sA2[(q * 4 + r) * 528 + col] = (bf16_t)fmaxf(h[j][r] + bb, 0.f);
    }
    __syncthreads();

    // ---- Stage E: mlp = h1@W2^T + b2 + residual
    f32x4 m4[4];
#pragma unroll
    for (int j = 0; j < 4; j++) m4[j] = (f32x4){0.f, 0.f, 0.f, 0.f};
    for (int k0 = 0; k0 < 512; k0 += 32) {
      bf16x8 aH = *(const bf16x8*)(sA2 + c * 528 + k0 + q * 8);
#pragma unroll
      for (int j = 0; j < 4; j++) {
        const long col = (w * 4 + j) * 16 + c;
        m4[j] = MFMA16(aH, *(const bf16x8*)(W2 + col * 512 + k0 + q * 8), m4[j]);
      }
    }
#pragma unroll
    for (int j = 0; j < 4; j++) {
      const int col = (w * 4 + j) * 16 + c;
      const float bb = b2[col];
#pragma unroll
      for (int r = 0; r < 4; r++) {
        const int row = q * 4 + r;
        float sfin = m4[j][r] + bb + sS[row][col];
        if constexpr (MODE == 2) {
          if (row < KS) d_out[((long)b * KS + row) * DD + col] = sfin;
        } else {
          sS[row][col] = sfin;
          slots_b[row * DD + col] = sfin;
        }
      }
    }
    if constexpr (MODE == 2) return;
  }

  // ---- LN_s stats + sln -> sA1
  rowstats();
  for (int idx = tid; idx < KP * DD; idx += 256) {
    int row = idx >> 8, d = idx & 255;
    sA1[row * 272 + d] = (bf16_t)((sS[row][d] - sMu[row]) * sRs[row] * ln_s_w[d] + ln_s_b[d]);
  }
  __syncthreads();

  // ---- Stage G: q = sln@Wq^T -> q_bf ; zero rowsum for next attention
  f32x4 qa[4];
#pragma unroll
  for (int j = 0; j < 4; j++) qa[j] = (f32x4){0.f, 0.f, 0.f, 0.f};
  for (int k0 = 0; k0 < 256; k0 += 32) {
    bf16x8 aL = *(const bf16x8*)(sA1 + c * 272 + k0 + q * 8);
#pragma unroll
    for (int j = 0; j < 4; j++) {
      const long col = (w * 4 + j) * 16 + c;
      qa[j] = MFMA16(aL, *(const bf16x8*)(Wq + col * 256 + k0 + q * 8), qa[j]);
    }
  }
  bf16_t* qb = q_bf + (long)b * KP * DD;
#pragma unroll
  for (int j = 0; j < 4; j++) {
    const int col = (w * 4 + j) * 16 + c;
#pragma unroll
    for (int r = 0; r < 4; r++) qb[(q * 4 + r) * DD + col] = (bf16_t)qa[j][r];
  }
  if (tid < KP) rowsum[b * KP + tid] = 0.f;
}

extern "C" void kernel_launch(void* const* d_in, const int* in_sizes, int n_in, void* d_out,
                              int out_size, void* d_ws, size_t ws_size, hipStream_t stream) {
  (void)in_sizes; (void)n_in; (void)out_size; (void)ws_size;
  const float* inputs = (const float*)d_in[0];
  const float* slots_in = (const float*)d_in[1];
  const float* ln_f_w = (const float*)d_in[2];
  const float* ln_f_b = (const float*)d_in[3];
  const float* ln_s_w = (const float*)d_in[4];
  const float* ln_s_b = (const float*)d_in[5];
  const float* ln_p_w = (const float*)d_in[6];
  const float* ln_p_b = (const float*)d_in[7];
  const float* Wq = (const float*)d_in[8];
  const float* Wk = (const float*)d_in[9];
  const float* Wv = (const float*)d_in[10];
  const float* W_ih = (const float*)d_in[11];
  const float* b_ih = (const float*)d_in[12];
  const float* W_hh = (const float*)d_in[13];
  const float* b_hh = (const float*)d_in[14];
  const float* W1 = (const float*)d_in[15];
  const float* b1 = (const float*)d_in[16];
  const float* W2 = (const float*)d_in[17];
  const float* b2 = (const float*)d_in[18];

  char* p = (char*)d_ws;
  auto alloc = [&](size_t bytes) { char* r = p; p += (bytes + 255) & ~(size_t)255; return r; };
  bf16_t* x_bf  = (bf16_t*)alloc((size_t)BB * NN * DD * 2);
  bf16_t* k_bf  = (bf16_t*)alloc((size_t)BB * NN * DD * 2);
  bf16_t* vT_bf = (bf16_t*)alloc((size_t)BB * NN * DD * 2);
  bf16_t* Wq_bf = (bf16_t*)alloc(65536 * 2);
  bf16_t* Wk_bf = (bf16_t*)alloc(65536 * 2);
  bf16_t* Wv_bf = (bf16_t*)alloc(65536 * 2);
  bf16_t* Wih_bf = (bf16_t*)alloc(196608 * 2);
  bf16_t* Whh_bf = (bf16_t*)alloc(196608 * 2);
  bf16_t* W1_bf = (bf16_t*)alloc(131072 * 2);
  bf16_t* W2_bf = (bf16_t*)alloc(131072 * 2);
  float* slots = (float*)alloc((size_t)MR * DD * 4);
  bf16_t* q_bf = (bf16_t*)alloc((size_t)MR * DD * 2);
  float* upd_part = (float*)alloc((size_t)BB * NSPLIT * KP * DD * 4);   // 8 MB
  float* rowsum = (float*)alloc((size_t)MR * 4);

  prep_weights_k<<<3328, 256, 0, stream>>>(Wq, Wk, Wv, W_ih, W_hh, W1, W2, Wq_bf, Wk_bf, Wv_bf,
                                           Wih_bf, Whh_bf, W1_bf, W2_bf);
  slot_update_k<0><<<BB, 256, 0, stream>>>(slots_in, slots, upd_part, rowsum, q_bf, nullptr,
                                           Wq_bf, Wih_bf, Whh_bf, W1_bf, W2_bf,
                                           b_ih, b_hh, b1, b2, ln_s_w, ln_s_b, ln_p_w, ln_p_b);
  ln_inputs_k<<<65536, 256, 0, stream>>>(inputs, ln_f_w, ln_f_b, x_bf);
  gemm_kv_k<<<4096, 256, 0, stream>>>(x_bf, Wk_bf, Wv_bf, k_bf, vT_bf);

  for (int t = 0; t < 5; t++) {
    fused_attn_k<<<BB * NSPLIT, 256, 0, stream>>>(q_bf, k_bf, vT_bf, upd_part, rowsum);
    if (t < 4)
      slot_update_k<1><<<BB, 256, 0, stream>>>(slots_in, slots, upd_part, rowsum, q_bf, nullptr,
                                               Wq_bf, Wih_bf, Whh_bf, W1_bf, W2_bf,
                                               b_ih, b_hh, b1, b2, ln_s_w, ln_s_b, ln_p_w, ln_p_b);
    else
      slot_update_k<2><<<BB, 256, 0, stream>>>(slots_in, slots, upd_part, rowsum, q_bf,
                                               (float*)d_out,
                                               Wq_bf, Wih_bf, Whh_bf, W1_bf, W2_bf,
                                               b_ih, b_hh, b1, b2, ln_s_w, ln_s_b, ln_p_w, ln_p_b);
  }
}

// Round 4
// 1243.536 us; speedup vs baseline: 1.0821x; 1.0821x over previous
//
#include <hip/hip_runtime.h>

typedef __bf16 bf16_t;
typedef bf16_t bf16x8 __attribute__((ext_vector_type(8)));
typedef bf16_t bf16x4 __attribute__((ext_vector_type(4)));
typedef float f32x4 __attribute__((ext_vector_type(4)));

#define DEVI static __device__ __forceinline__
#define MFMA16(a, b, c) __builtin_amdgcn_mfma_f32_16x16x32_bf16((a), (b), (c), 0, 0, 0)

constexpr int BB = 64;
constexpr int NN = 4096;
constexpr int DD = 256;
constexpr int KS = 11;     // real slots
constexpr int KP = 16;     // padded slots (MFMA tile)
constexpr float EPS_A = 1e-8f;
constexpr float LNEPS = 1e-5f;
constexpr float SCALE = 0.0625f;   // 256^-0.5
constexpr int MR = BB * KP;        // 1024 padded slot rows
constexpr int NSPLIT = 16;         // blocks per batch in fused attention (256 n each)
constexpr int ASTR = 136;          // attn LDS row stride (elements): 272B, 16B-aligned

DEVI float wredf(float v) {
#pragma unroll
  for (int o = 32; o > 0; o >>= 1) v += __shfl_xor(v, o, 64);
  return v;
}

DEVI float sigm(float x) { return 1.f / (1.f + __expf(-x)); }

// ---------------- prep: fp32 -> bf16 weights ----------------
__global__ void prep_weights_k(
    const float* __restrict__ s0, const float* __restrict__ s1, const float* __restrict__ s2,
    const float* __restrict__ s3, const float* __restrict__ s4, const float* __restrict__ s5,
    const float* __restrict__ s6,
    bf16_t* d0, bf16_t* d1, bf16_t* d2, bf16_t* d3, bf16_t* d4, bf16_t* d5, bf16_t* d6) {
  int i = blockIdx.x * 256 + threadIdx.x;
  const float* s; bf16_t* d; int o;
  if      (i < 65536)  { s = s0; d = d0; o = i; }
  else if (i < 131072) { s = s1; d = d1; o = i - 65536; }
  else if (i < 196608) { s = s2; d = d2; o = i - 131072; }
  else if (i < 393216) { s = s3; d = d3; o = i - 196608; }
  else if (i < 589824) { s = s4; d = d4; o = i - 393216; }
  else if (i < 720896) { s = s5; d = d5; o = i - 589824; }
  else                 { s = s6; d = d6; o = i - 720896; }
  d[o] = (bf16_t)s[o];
}

// ---------------- FUSED LN(inputs) + k/vT projection ----------------
// grid: BB*NN/64 = 4096 blocks, 256 thr. Block: 64 x-rows of one batch.
// k[b][n][d] = LN(x)@Wk^T ; vT[b][d][n] = (LN(x)@Wv^T)^T
__global__ __launch_bounds__(256) void ln_gemm_kv_k(const float* __restrict__ x,
                                                    const float* __restrict__ lnw,
                                                    const float* __restrict__ lnb,
                                                    const bf16_t* __restrict__ Wk,
                                                    const bf16_t* __restrict__ Wv,
                                                    bf16_t* __restrict__ kout,
                                                    bf16_t* __restrict__ vout) {
  __shared__ bf16_t xs[64 * 264];   // stride 264 el = 132 dw (== 4 mod 8: 2-way banks only)
  const long row0 = (long)blockIdx.x * 64;   // global x row
  const int b = (int)(row0 >> 12);
  const int n0 = (int)(row0 & 4095);
  const int tid = threadIdx.x, w = tid >> 6, lane = tid & 63;
  const int c = lane & 15, q = lane >> 4;

  // ---- stage 1: LN, one wave per row, 16 passes ----
#pragma unroll 4
  for (int pass = 0; pass < 16; ++pass) {
    const int r = pass * 4 + w;
    const float4 v = ((const float4*)(x + (row0 + r) * DD))[lane];
    float s = v.x + v.y + v.z + v.w;
    float s2 = v.x * v.x + v.y * v.y + v.z * v.z + v.w * v.w;
    s = wredf(s); s2 = wredf(s2);
    const float mean = s * (1.f / DD);
    const float var = s2 * (1.f / DD) - mean * mean;
    const float rstd = rsqrtf(var + LNEPS);
    const float4 w4 = ((const float4*)lnw)[lane];
    const float4 b4 = ((const float4*)lnb)[lane];
    bf16x4 ov;
    ov[0] = (bf16_t)((v.x - mean) * rstd * w4.x + b4.x);
    ov[1] = (bf16_t)((v.y - mean) * rstd * w4.y + b4.y);
    ov[2] = (bf16_t)((v.z - mean) * rstd * w4.z + b4.z);
    ov[3] = (bf16_t)((v.w - mean) * rstd * w4.w + b4.w);
    *(bf16x4*)(xs + r * 264 + lane * 4) = ov;
  }
  __syncthreads();

  // ---- part A: k-proj. A = Wk rows (d, wave w owns d-range w*64), B = xs rows ----
  {
    f32x4 acc[4][4];
#pragma unroll
    for (int mt = 0; mt < 4; mt++)
#pragma unroll
      for (int j = 0; j < 4; j++) acc[mt][j] = (f32x4){0.f, 0.f, 0.f, 0.f};
    for (int k0 = 0; k0 < 256; k0 += 32) {
      bf16x8 bfr[4];
#pragma unroll
      for (int j = 0; j < 4; j++)
        bfr[j] = *(const bf16x8*)(xs + (j * 16 + c) * 264 + k0 + q * 8);
#pragma unroll
      for (int mt = 0; mt < 4; mt++) {
        bf16x8 af = *(const bf16x8*)(Wk + (long)(w * 64 + mt * 16 + c) * 256 + k0 + q * 8);
#pragma unroll
        for (int j = 0; j < 4; j++) acc[mt][j] = MFMA16(af, bfr[j], acc[mt][j]);
      }
    }
#pragma unroll
    for (int mt = 0; mt < 4; mt++)
#pragma unroll
      for (int j = 0; j < 4; j++) {
        bf16x4 o;
#pragma unroll
        for (int r = 0; r < 4; r++) o[r] = (bf16_t)acc[mt][j][r];
        *(bf16x4*)(kout + (row0 + j * 16 + c) * DD + w * 64 + mt * 16 + q * 4) = o;
      }
  }

  // ---- part B: vT-proj. A = xs rows (x-rows), B = Wv rows (d, wave w owns w*64) ----
  {
    f32x4 acc[4][4];
#pragma unroll
    for (int mt = 0; mt < 4; mt++)
#pragma unroll
      for (int j = 0; j < 4; j++) acc[mt][j] = (f32x4){0.f, 0.f, 0.f, 0.f};
    for (int k0 = 0; k0 < 256; k0 += 32) {
      bf16x8 af[4];
#pragma unroll
      for (int mt = 0; mt < 4; mt++)
        af[mt] = *(const bf16x8*)(xs + (mt * 16 + c) * 264 + k0 + q * 8);
#pragma unroll
      for (int j = 0; j < 4; j++) {
        bf16x8 bfr = *(const bf16x8*)(Wv + (long)(w * 64 + j * 16 + c) * 256 + k0 + q * 8);
#pragma unroll
        for (int mt = 0; mt < 4; mt++) acc[mt][j] = MFMA16(af[mt], bfr, acc[mt][j]);
      }
    }
#pragma unroll
    for (int mt = 0; mt < 4; mt++)
#pragma unroll
      for (int j = 0; j < 4; j++) {
        bf16x4 o;
#pragma unroll
        for (int r = 0; r < 4; r++) o[r] = (bf16_t)acc[mt][j][r];
        const int d = w * 64 + j * 16 + c;
        *(bf16x4*)(vout + ((long)b * DD + d) * NN + n0 + mt * 16 + q * 4) = o;
      }
  }
}

// ---------------- FUSED attention, phase-split: dots+softmax -> LDS -> PV ----------------
// grid: BB*NSPLIT blocks (256 n each), 256 thr. Per chunk of 128 n: each wave does
// dots+softmax for its 32-n slice into LDS (dbuf), barrier, then PV for its 64-d slice.
__global__ __launch_bounds__(256) void fused_attn_k(const bf16_t* __restrict__ q_bf,
                                                    const bf16_t* __restrict__ k_bf,
                                                    const bf16_t* __restrict__ vT_bf,
                                                    float* __restrict__ upd_part,
                                                    float* __restrict__ rowsum) {
  const int b = blockIdx.x / NSPLIT, sp = blockIdx.x % NSPLIT;
  const int w = threadIdx.x >> 6, lane = threadIdx.x & 63;
  const int c = lane & 15, q = lane >> 4;

  __shared__ bf16_t att_s[2][16 * ASTR];

  const bf16_t* qp = q_bf + (long)b * KP * DD;
  bf16x8 af[8];
#pragma unroll
  for (int kc = 0; kc < 8; kc++) af[kc] = *(const bf16x8*)(qp + c * DD + kc * 32 + q * 8);

  f32x4 pacc[4];
#pragma unroll
  for (int j = 0; j < 4; j++) pacc[j] = (f32x4){0.f, 0.f, 0.f, 0.f};
  float rs[4] = {0.f, 0.f, 0.f, 0.f};

  const int nb0 = sp * (NN / NSPLIT);
  const bf16_t* kp = k_bf + (long)b * NN * DD;
  const bf16_t* vp = vT_bf + (long)b * DD * NN;

  for (int chunk = 0; chunk < 2; ++chunk) {
    const int n0 = nb0 + chunk * 128;
    const int nw = n0 + w * 32;
    bf16_t* as = att_s[chunk & 1];
    // ---- dots + softmax for this wave's 32 columns ----
#pragma unroll
    for (int t = 0; t < 2; t++) {
      const bf16_t* bp = kp + (long)(nw + t * 16 + c) * DD + q * 8;
      f32x4 d0 = (f32x4){0.f, 0.f, 0.f, 0.f}, d1 = (f32x4){0.f, 0.f, 0.f, 0.f};
#pragma unroll
      for (int kc = 0; kc < 4; kc++) {
        d0 = MFMA16(af[2 * kc],     *(const bf16x8*)(bp + kc * 64),      d0);
        d1 = MFMA16(af[2 * kc + 1], *(const bf16x8*)(bp + kc * 64 + 32), d1);
      }
      float v[4];
#pragma unroll
      for (int r = 0; r < 4; r++) {
        float dv = (d0[r] + d1[r]) * SCALE;
        if (q * 4 + r >= KS) dv = -1e30f;   // mask pad slots
        v[r] = dv;
      }
      float m4 = fmaxf(fmaxf(v[0], v[1]), fmaxf(v[2], v[3]));
      m4 = fmaxf(m4, __shfl_xor(m4, 16, 64));
      m4 = fmaxf(m4, __shfl_xor(m4, 32, 64));
      float s4 = 0.f;
#pragma unroll
      for (int r = 0; r < 4; r++) { v[r] = __expf(v[r] - m4); s4 += v[r]; }
      s4 += __shfl_xor(s4, 16, 64);
      s4 += __shfl_xor(s4, 32, 64);
      const float inv = 1.f / s4;
#pragma unroll
      for (int r = 0; r < 4; r++) {
        float a = v[r] * inv + EPS_A;
        rs[r] += a;
        as[(q * 4 + r) * ASTR + (w * 32 + t * 16 + c)] = (bf16_t)a;
      }
    }
    __syncthreads();
    // ---- PV: wave w owns d-range w*64, K = these 128 n ----
#pragma unroll
    for (int ns = 0; ns < 4; ns++) {
      bf16x8 pa = *(const bf16x8*)(as + c * ASTR + ns * 32 + q * 8);
#pragma unroll
      for (int j = 0; j < 4; j++) {
        const bf16_t* bp2 = vp + (long)(w * 64 + j * 16 + c) * NN + n0 + ns * 32 + q * 8;
        pacc[j] = MFMA16(pa, *(const bf16x8*)bp2, pacc[j]);
      }
    }
  }

  // rowsum: reduce over 16 c-lanes in each q-group, atomic per slot
#pragma unroll
  for (int off = 1; off < 16; off <<= 1)
#pragma unroll
    for (int r = 0; r < 4; r++) rs[r] += __shfl_xor(rs[r], off, 64);
  if (c == 0) {
#pragma unroll
    for (int r = 0; r < 4; r++) atomicAdd(&rowsum[b * KP + q * 4 + r], rs[r]);
  }

  // per-block partial: upd_part[bid][slot][d]; waves own disjoint d-ranges
  float* up = upd_part + (long)blockIdx.x * (KP * DD);
#pragma unroll
  for (int j = 0; j < 4; j++)
#pragma unroll
    for (int r = 0; r < 4; r++) up[(q * 4 + r) * DD + w * 64 + j * 16 + c] = pacc[j][r];
}

// ---------------- slot update mega-kernel: one block per batch ----------------
template <int MODE>   // 0: init, 1: mid-iter, 2: last iter -> d_out
__global__ __launch_bounds__(256) void slot_update_k(
    const float* __restrict__ slots_init, float* __restrict__ slots_g,
    const float* __restrict__ upd_part, float* __restrict__ rowsum,
    bf16_t* __restrict__ q_bf, float* __restrict__ d_out,
    const bf16_t* __restrict__ Wq, const bf16_t* __restrict__ Wih,
    const bf16_t* __restrict__ Whh, const bf16_t* __restrict__ W1,
    const bf16_t* __restrict__ W2,
    const float* __restrict__ b_ih, const float* __restrict__ b_hh,
    const float* __restrict__ b1, const float* __restrict__ b2,
    const float* __restrict__ ln_s_w, const float* __restrict__ ln_s_b,
    const float* __restrict__ ln_p_w, const float* __restrict__ ln_p_b) {
  const int b = blockIdx.x;
  const int tid = threadIdx.x, w = tid >> 6, lane = tid & 63;
  const int c = lane & 15, q = lane >> 4;

  __shared__ float sS[16][264];
  __shared__ bf16_t sA1[16 * 272];
  __shared__ bf16_t sA2[16 * 528];
  __shared__ float sMu[16], sRs[16];

  float* slots_b = slots_g + (long)b * KP * DD;

  auto rowstats = [&]() {
    __syncthreads();
    int row = w * 4 + q;
    float sm = 0.f, sq2 = 0.f;
#pragma unroll
    for (int i = 0; i < 16; i++) { float v = sS[row][i * 16 + c]; sm += v; sq2 += v * v; }
#pragma unroll
    for (int o = 1; o < 16; o <<= 1) { sm += __shfl_xor(sm, o, 64); sq2 += __shfl_xor(sq2, o, 64); }
    if (c == 0) {
      float mu = sm * (1.f / 256.f);
      float var = sq2 * (1.f / 256.f) - mu * mu;
      sMu[row] = mu; sRs[row] = rsqrtf(var + LNEPS);
    }
    __syncthreads();
  };

  if constexpr (MODE == 0) {
    for (int idx = tid; idx < KP * DD; idx += 256) {
      int row = idx >> 8, d = idx & 255;
      float v = (row < KS) ? slots_init[((long)b * KS + row) * DD + d] : 0.f;
      sS[row][d] = v;
      slots_b[idx] = v;
    }
  } else {
    for (int idx = tid; idx < KP * DD; idx += 256) {
      int row = idx >> 8, d = idx & 255;
      float sv = slots_b[idx];
      sS[row][d] = sv;
      sA2[row * 272 + d] = (bf16_t)sv;
      float s = 0.f;
      const float* up = upd_part + ((long)b * NSPLIT) * (KP * DD) + idx;
#pragma unroll
      for (int p = 0; p < NSPLIT; p++) s += up[(long)p * (KP * DD)];
      sA1[row * 272 + d] = (bf16_t)(s / rowsum[b * KP + row]);
    }
    __syncthreads();

    // GRU gates
    f32x4 air[4], aiz[4], ain[4], ahr[4], ahz[4], ahn[4];
#pragma unroll
    for (int j = 0; j < 4; j++) {
      air[j] = (f32x4){0.f, 0.f, 0.f, 0.f}; aiz[j] = air[j]; ain[j] = air[j];
      ahr[j] = air[j]; ahz[j] = air[j]; ahn[j] = air[j];
    }
    for (int k0 = 0; k0 < 256; k0 += 32) {
      bf16x8 aU = *(const bf16x8*)(sA1 + c * 272 + k0 + q * 8);
      bf16x8 aS = *(const bf16x8*)(sA2 + c * 272 + k0 + q * 8);
#pragma unroll
      for (int j = 0; j < 4; j++) {
        const long colr = (w * 4 + j) * 16 + c;
        air[j] = MFMA16(aU, *(const bf16x8*)(Wih + colr * 256 + k0 + q * 8), air[j]);
        aiz[j] = MFMA16(aU, *(const bf16x8*)(Wih + (colr + 256) * 256 + k0 + q * 8), aiz[j]);
        ain[j] = MFMA16(aU, *(const bf16x8*)(Wih + (colr + 512) * 256 + k0 + q * 8), ain[j]);
        ahr[j] = MFMA16(aS, *(const bf16x8*)(Whh + colr * 256 + k0 + q * 8), ahr[j]);
        ahz[j] = MFMA16(aS, *(const bf16x8*)(Whh + (colr + 256) * 256 + k0 + q * 8), ahz[j]);
        ahn[j] = MFMA16(aS, *(const bf16x8*)(Whh + (colr + 512) * 256 + k0 + q * 8), ahn[j]);
      }
    }
#pragma unroll
    for (int j = 0; j < 4; j++) {
      const int colr = (w * 4 + j) * 16 + c;
      const float bir = b_ih[colr], biz = b_ih[colr + 256], bin = b_ih[colr + 512];
      const float bhr = b_hh[colr], bhz = b_hh[colr + 256], bhn = b_hh[colr + 512];
#pragma unroll
      for (int r = 0; r < 4; r++) {
        const int row = q * 4 + r;
        float rg = sigm(air[j][r] + bir + ahr[j][r] + bhr);
        float zg = sigm(aiz[j][r] + biz + ahz[j][r] + bhz);
        float ng = tanhf(ain[j][r] + bin + rg * (ahn[j][r] + bhn));
        float sp = sS[row][colr];
        sS[row][colr] = (1.f - zg) * ng + zg * sp;
      }
    }

    rowstats();
    for (int idx = tid; idx < KP * DD; idx += 256) {
      int row = idx >> 8, d = idx & 255;
      sA1[row * 272 + d] = (bf16_t)((sS[row][d] - sMu[row]) * sRs[row] * ln_p_w[d] + ln_p_b[d]);
    }
    __syncthreads();

    // h1 = relu(pbf@W1^T + b1)
    f32x4 h[8];
#pragma unroll
    for (int j = 0; j < 8; j++) h[j] = (f32x4){0.f, 0.f, 0.f, 0.f};
    for (int k0 = 0; k0 < 256; k0 += 32) {
      bf16x8 aP = *(const bf16x8*)(sA1 + c * 272 + k0 + q * 8);
#pragma unroll
      for (int j = 0; j < 8; j++) {
        const long col = (w * 8 + j) * 16 + c;
        h[j] = MFMA16(aP, *(const bf16x8*)(W1 + col * 256 + k0 + q * 8), h[j]);
      }
    }
#pragma unroll
    for (int j = 0; j < 8; j++) {
      const int col = (w * 8 + j) * 16 + c;
      const float bb = b1[col];
#pragma unroll
      for (int r = 0; r < 4; r++)
        sA2[(q * 4 + r) * 528 + col] = (bf16_t)fmaxf(h[j][r] + bb, 0.f);
    }
    __syncthreads();

    // mlp out + residual
    f32x4 m4[4];
#pragma unroll
    for (int j = 0; j < 4; j++) m4[j] = (f32x4){0.f, 0.f, 0.f, 0.f};
    for (int k0 = 0; k0 < 512; k0 += 32) {
      bf16x8 aH = *(const bf16x8*)(sA2 + c * 528 + k0 + q * 8);
#pragma unroll
      for (int j = 0; j < 4; j++) {
        const long col = (w * 4 + j) * 16 + c;
        m4[j] = MFMA16(aH, *(const bf16x8*)(W2 + col * 512 + k0 + q * 8), m4[j]);
      }
    }
#pragma unroll
    for (int j = 0; j < 4; j++) {
      const int col = (w * 4 + j) * 16 + c;
      const float bb = b2[col];
#pragma unroll
      for (int r = 0; r < 4; r++) {
        const int row = q * 4 + r;
        float sfin = m4[j][r] + bb + sS[row][col];
        if constexpr (MODE == 2) {
          if (row < KS) d_out[((long)b * KS + row) * DD + col] = sfin;
        } else {
          sS[row][col] = sfin;
          slots_b[row * DD + col] = sfin;
        }
      }
    }
    if constexpr (MODE == 2) return;
  }

  rowstats();
  for (int idx = tid; idx < KP * DD; idx += 256) {
    int row = idx >> 8, d = idx & 255;
    sA1[row * 272 + d] = (bf16_t)((sS[row][d] - sMu[row]) * sRs[row] * ln_s_w[d] + ln_s_b[d]);
  }
  __syncthreads();

  // q = sln@Wq^T
  f32x4 qa[4];
#pragma unroll
  for (int j = 0; j < 4; j++) qa[j] = (f32x4){0.f, 0.f, 0.f, 0.f};
  for (int k0 = 0; k0 < 256; k0 += 32) {
    bf16x8 aL = *(const bf16x8*)(sA1 + c * 272 + k0 + q * 8);
#pragma unroll
    for (int j = 0; j < 4; j++) {
      const long col = (w * 4 + j) * 16 + c;
      qa[j] = MFMA16(aL, *(const bf16x8*)(Wq + col * 256 + k0 + q * 8), qa[j]);
    }
  }
  bf16_t* qb = q_bf + (long)b * KP * DD;
#pragma unroll
  for (int j = 0; j < 4; j++) {
    const int col = (w * 4 + j) * 16 + c;
#pragma unroll
    for (int r = 0; r < 4; r++) qb[(q * 4 + r) * DD + col] = (bf16_t)qa[j][r];
  }
  if (tid < KP) rowsum[b * KP + tid] = 0.f;
}

extern "C" void kernel_launch(void* const* d_in, const int* in_sizes, int n_in, void* d_out,
                              int out_size, void* d_ws, size_t ws_size, hipStream_t stream) {
  (void)in_sizes; (void)n_in; (void)out_size; (void)ws_size;
  const float* inputs = (const float*)d_in[0];
  const float* slots_in = (const float*)d_in[1];
  const float* ln_f_w = (const float*)d_in[2];
  const float* ln_f_b = (const float*)d_in[3];
  const float* ln_s_w = (const float*)d_in[4];
  const float* ln_s_b = (const float*)d_in[5];
  const float* ln_p_w = (const float*)d_in[6];
  const float* ln_p_b = (const float*)d_in[7];
  const float* Wq = (const float*)d_in[8];
  const float* Wk = (const float*)d_in[9];
  const float* Wv = (const float*)d_in[10];
  const float* W_ih = (const float*)d_in[11];
  const float* b_ih = (const float*)d_in[12];
  const float* W_hh = (const float*)d_in[13];
  const float* b_hh = (const float*)d_in[14];
  const float* W1 = (const float*)d_in[15];
  const float* b1 = (const float*)d_in[16];
  const float* W2 = (const float*)d_in[17];
  const float* b2 = (const float*)d_in[18];

  char* p = (char*)d_ws;
  auto alloc = [&](size_t bytes) { char* r = p; p += (bytes + 255) & ~(size_t)255; return r; };
  bf16_t* k_bf  = (bf16_t*)alloc((size_t)BB * NN * DD * 2);
  bf16_t* vT_bf = (bf16_t*)alloc((size_t)BB * NN * DD * 2);
  bf16_t* Wq_bf = (bf16_t*)alloc(65536 * 2);
  bf16_t* Wk_bf = (bf16_t*)alloc(65536 * 2);
  bf16_t* Wv_bf = (bf16_t*)alloc(65536 * 2);
  bf16_t* Wih_bf = (bf16_t*)alloc(196608 * 2);
  bf16_t* Whh_bf = (bf16_t*)alloc(196608 * 2);
  bf16_t* W1_bf = (bf16_t*)alloc(131072 * 2);
  bf16_t* W2_bf = (bf16_t*)alloc(131072 * 2);
  float* slots = (float*)alloc((size_t)MR * DD * 4);
  bf16_t* q_bf = (bf16_t*)alloc((size_t)MR * DD * 2);
  float* upd_part = (float*)alloc((size_t)BB * NSPLIT * KP * DD * 4);   // 16 MB
  float* rowsum = (float*)alloc((size_t)MR * 4);

  prep_weights_k<<<3328, 256, 0, stream>>>(Wq, Wk, Wv, W_ih, W_hh, W1, W2, Wq_bf, Wk_bf, Wv_bf,
                                           Wih_bf, Whh_bf, W1_bf, W2_bf);
  slot_update_k<0><<<BB, 256, 0, stream>>>(slots_in, slots, upd_part, rowsum, q_bf, nullptr,
                                           Wq_bf, Wih_bf, Whh_bf, W1_bf, W2_bf,
                                           b_ih, b_hh, b1, b2, ln_s_w, ln_s_b, ln_p_w, ln_p_b);
  ln_gemm_kv_k<<<BB * NN / 64, 256, 0, stream>>>(inputs, ln_f_w, ln_f_b, Wk_bf, Wv_bf, k_bf, vT_bf);

  for (int t = 0; t < 5; t++) {
    fused_attn_k<<<BB * NSPLIT, 256, 0, stream>>>(q_bf, k_bf, vT_bf, upd_part, rowsum);
    if (t < 4)
      slot_update_k<1><<<BB, 256, 0, stream>>>(slots_in, slots, upd_part, rowsum, q_bf, nullptr,
                                               Wq_bf, Wih_bf, Whh_bf, W1_bf, W2_bf,
                                               b_ih, b_hh, b1, b2, ln_s_w, ln_s_b, ln_p_w, ln_p_b);
    else
      slot_update_k<2><<<BB, 256, 0, stream>>>(slots_in, slots, upd_part, rowsum, q_bf,
                                               (float*)d_out,
                                               Wq_bf, Wih_bf, Whh_bf, W1_bf, W2_bf,
                                               b_ih, b_hh, b1, b2, ln_s_w, ln_s_b, ln_p_w, ln_p_b);
  }
}